// Round 4
// baseline (2550.507 us; speedup 1.0000x reference)
//
#include <hip/hip_runtime.h>
#include <stdint.h>

typedef short bf16x8 __attribute__((ext_vector_type(8)));
typedef float f32x4 __attribute__((ext_vector_type(4)));

#define NPOS 65536  // B*L = 64*1024
#define MB (1024ull * 1024ull)
#define SK_PIECE 2097152  // shorts per 4MB piece of the in-place skip output

__device__ __forceinline__ unsigned short f32_bf16(float f) {
    union { float f; unsigned u; } v; v.f = f;
    unsigned u = v.u;
    u += 0x7fffu + ((u >> 16) & 1u);
    return (unsigned short)(u >> 16);
}

// load 8 consecutive floats, round to bf16 fragment (scalar path)
__device__ __forceinline__ bf16x8 ldf8_bf16(const float* p) {
    const float4 lo = *(const float4*)p;
    const float4 hi = *(const float4*)(p + 4);
    bf16x8 v;
    v[0] = (short)f32_bf16(lo.x); v[1] = (short)f32_bf16(lo.y);
    v[2] = (short)f32_bf16(lo.z); v[3] = (short)f32_bf16(lo.w);
    v[4] = (short)f32_bf16(hi.x); v[5] = (short)f32_bf16(hi.y);
    v[6] = (short)f32_bf16(hi.z); v[7] = (short)f32_bf16(hi.w);
    return v;
}

__device__ __forceinline__ bf16x8 pack_bf16(float4 lo, float4 hi) {
    bf16x8 v;
    v[0] = (short)f32_bf16(lo.x); v[1] = (short)f32_bf16(lo.y);
    v[2] = (short)f32_bf16(lo.z); v[3] = (short)f32_bf16(lo.w);
    v[4] = (short)f32_bf16(hi.x); v[5] = (short)f32_bf16(hi.y);
    v[6] = (short)f32_bf16(hi.z); v[7] = (short)f32_bf16(hi.w);
    return v;
}

// fallback: encode ws_size (MiB) into output so a failing run tells us the budget
__global__ void ws_probe_k(float* __restrict__ out, float mib) {
    int i = blockIdx.x * 256 + threadIdx.x;
    if (i < 16384) out[i] = mib;
}

// ---- repack filter+gate weights (fp32 in) -> bf16 [layer][tap][oc 0..63 (f|g)][ic 0..31]
__global__ void repack_fgw_k(const float* __restrict__ fw,
                             const float* __restrict__ gw,
                             unsigned short* __restrict__ out) {
    int idx = blockIdx.x * 256 + threadIdx.x;  // < 40*3*64*32 = 245760
    int ic = idx & 31;
    int r1 = idx >> 5;
    int oc = r1 & 63;
    int r2 = r1 >> 6;      // i*3 + k
    int k  = r2 % 3;
    int i  = r2 / 3;
    const float* src = (oc < 32) ? fw : gw;
    out[idx] = f32_bf16(src[(((i * 32 + (oc & 31)) * 32 + ic) * 3) + k]);
}

// ---- repack skip weights fp32 -> bf16, same layout [40][256][32]
__global__ void repack_sw_k(const float* __restrict__ sw,
                            unsigned short* __restrict__ out) {
    int idx = blockIdx.x * 256 + threadIdx.x;  // < 40*256*32 = 327680
    out[idx] = f32_bf16(sw[idx]);
}

// ---- repack residual weights fp32 -> bf16 linear [40][32][32]
__global__ void repack_rw_k(const float* __restrict__ rw,
                            unsigned short* __restrict__ out) {
    int idx = blockIdx.x * 256 + threadIdx.x;  // < 40*32*32 = 40960
    out[idx] = f32_bf16(rw[idx]);
}

__global__ void zero_progress_k(int* __restrict__ p) {
    p[blockIdx.x * 256 + threadIdx.x] = 0;   // grid 4 -> 1024 ints
}

// ---- start conv: x0[p][c] fp32, p = b*1024 + t
__global__ void start_conv_k(const float* __restrict__ in,
                             const float* __restrict__ sw,
                             float* __restrict__ x0) {
    int tid = threadIdx.x;
    int p = blockIdx.x * 64 + (tid >> 2);
    int c0 = (tid & 3) * 8;
    int b = p >> 10, t = p & 1023;
    float i0 = in[(b * 2 + 0) * 1024 + t];
    float i1 = in[(b * 2 + 1) * 1024 + t];
    float o[8];
#pragma unroll
    for (int j = 0; j < 8; ++j) {
        int c = c0 + j;
        o[j] = sw[c * 2 + 0] * i0 + sw[c * 2 + 1] * i1;
    }
    float4* dst = (float4*)(x0 + (size_t)p * 32 + c0);
    dst[0] = make_float4(o[0], o[1], o[2], o[3]);
    dst[1] = make_float4(o[4], o[5], o[6], o[7]);
}

// ---- ALL 40 WaveNet layers in ONE persistent kernel.
// Block pb owns positions [pb*64, pb*64+64) for the whole stack.
// Cross-block deps are row-local (taps reach +-d, d<=512 < row length 1024),
// enforced by per-block progress counters + neighbor spin-waits
// (radius r = ceil(max(d_i, d_{i-1})/64) <= 8, same batch row only).
// All 1024 blocks co-resident: 4 blocks/CU (256 thr, 14.3KB LDS, <=128 VGPR).
__global__ __launch_bounds__(256, 4) void layers_fused_k(
    float* __restrict__ xa, float* __restrict__ xb,    // xa = start conv output
    const unsigned short* __restrict__ fgw_all,        // [40][3][64][32] bf16
    const unsigned short* __restrict__ rwb_all,        // [40][32][32] bf16
    unsigned short* __restrict__ xg_all,               // [40][65536][32] bf16
    int* __restrict__ progress)                        // [1024], zeroed
{
    __shared__ __align__(16) unsigned short lds1[64 * 40]; // xg tile [pos][ch pad40]
    __shared__ __align__(16) float lds2[64 * 36];          // res tile [pos][ch pad36]
    const int tid = threadIdx.x;
    const int w = tid >> 6, lane = tid & 63;
    const int quad = lane >> 4, l15 = lane & 15;
    const int pb = blockIdx.x;
    const int p0 = pb * 64;
    const int b = p0 >> 10, t0 = p0 & 1023;
    const int row0 = pb & ~15;               // first tile of this batch row
    const int posl = w * 16 + l15;           // 0..63
    const int tpos = t0 + posl;
    const int ch0 = quad * 8;
    const f32x4 zero = {0.f, 0.f, 0.f, 0.f};

    for (int i = 0; i < 40; ++i) {
        const int d = 1 << (i % 10);

        // ---- wait for neighbors to finish layer i-1 (RAW + WAR radius)
        if (i > 0) {
            const int dp = 1 << ((i - 1) % 10);
            const int dm = d > dp ? d : dp;
            const int r = (dm + 63) >> 6;
            int nlo = pb - r; if (nlo < row0) nlo = row0;
            int nhi = pb + r; if (nhi > row0 + 15) nhi = row0 + 15;
            if (tid <= nhi - nlo) {
                while (__hip_atomic_load(progress + nlo + tid, __ATOMIC_ACQUIRE,
                                         __HIP_MEMORY_SCOPE_AGENT) < i)
                    __builtin_amdgcn_s_sleep(2);
            }
            __syncthreads();
        }

        const float* __restrict__ xin = (i & 1) ? xb : xa;
        float* __restrict__ xout      = (i & 1) ? xa : xb;
        const unsigned short* fgw = fgw_all + (size_t)i * 6144;
        unsigned short* xg = xg_all + (size_t)i * ((size_t)NPOS * 32);

        // ---- taps (keep center fp32 for the residual epilogue)
        float4 clo, chi;
        bf16x8 bfr[3];
        {
            const float* cp = xin + ((size_t)(b * 1024 + tpos)) * 32 + ch0;
            clo = *(const float4*)cp;
            chi = *(const float4*)(cp + 4);
            bfr[1] = pack_bf16(clo, chi);
        }
#pragma unroll
        for (int k = 0; k < 3; k += 2) {
            int ts = tpos + (k - 1) * d;
            bf16x8 v;
#pragma unroll
            for (int j = 0; j < 8; ++j) v[j] = 0;
            if (ts >= 0 && ts < 1024)
                v = ldf8_bf16(xin + ((size_t)(b * 1024 + ts)) * 32 + ch0);
            bfr[k] = v;
        }

        // ---- dilated conv (filter+gate) via MFMA
        f32x4 accf[2] = {zero, zero};
        f32x4 accg[2] = {zero, zero};
#pragma unroll
        for (int k = 0; k < 3; ++k) {
            const unsigned short* wb = fgw + (size_t)k * 2048;
#pragma unroll
            for (int mt = 0; mt < 2; ++mt) {
                bf16x8 af = *(const bf16x8*)(wb + (mt * 16 + l15) * 32 + ch0);
                accf[mt] = __builtin_amdgcn_mfma_f32_16x16x32_bf16(af, bfr[k], accf[mt], 0, 0, 0);
            }
#pragma unroll
            for (int mt = 0; mt < 2; ++mt) {
                bf16x8 ag = *(const bf16x8*)(wb + ((mt + 2) * 16 + l15) * 32 + ch0);
                accg[mt] = __builtin_amdgcn_mfma_f32_16x16x32_bf16(ag, bfr[k], accg[mt], 0, 0, 0);
            }
        }

        // ---- gated activation -> bf16 xg into LDS
#pragma unroll
        for (int mt = 0; mt < 2; ++mt)
#pragma unroll
            for (int r = 0; r < 4; ++r) {
                float fv = accf[mt][r], gv = accg[mt][r];
                float th = 1.0f - 2.0f / (1.0f + __expf(2.0f * fv));
                float sg = 1.0f / (1.0f + __expf(-gv));
                lds1[posl * 40 + mt * 16 + quad * 4 + r] = f32_bf16(th * sg);
            }
        __syncthreads();

        // ---- coalesced xg store
        {
            int pp = tid >> 2, c0s = (tid & 3) * 8;
            int4 v = *(const int4*)(lds1 + pp * 40 + c0s);
            *(int4*)(xg + ((size_t)(p0 + pp)) * 32 + c0s) = v;
        }

        // ---- res 1x1 GEMM (skip for last layer: its x output is never used)
        if (i < 39) {
            bf16x8 bx = *(const bf16x8*)(lds1 + posl * 40 + ch0);
            const unsigned short* rwb = rwb_all + (size_t)i * 1024;
            f32x4 accr[2] = {zero, zero};
#pragma unroll
            for (int rt = 0; rt < 2; ++rt) {
                bf16x8 ar = *(const bf16x8*)(rwb + (rt * 16 + l15) * 32 + ch0);
                accr[rt] = __builtin_amdgcn_mfma_f32_16x16x32_bf16(ar, bx, accr[rt], 0, 0, 0);
            }
#pragma unroll
            for (int rt = 0; rt < 2; ++rt)
#pragma unroll
                for (int r = 0; r < 4; ++r)
                    lds2[posl * 36 + rt * 16 + quad * 4 + r] = accr[rt][r];
        }
        __syncthreads();

        // ---- x_new = res + x_old (center tap reused from registers)
        if (i < 39) {
            float* xo = xout + ((size_t)(p0 + posl)) * 32 + ch0;
            float4 d0 = *(const float4*)(lds2 + posl * 36 + ch0);
            float4 d1 = *(const float4*)(lds2 + posl * 36 + ch0 + 4);
            *(float4*)(xo)     = make_float4(clo.x + d0.x, clo.y + d0.y, clo.z + d0.z, clo.w + d0.w);
            *(float4*)(xo + 4) = make_float4(chi.x + d1.x, chi.y + d1.y, chi.z + d1.z, chi.w + d1.w);
            __syncthreads();   // drain all waves' stores before publishing
            if (tid == 0)
                __hip_atomic_store(progress + pb, i + 1, __ATOMIC_RELEASE,
                                   __HIP_MEMORY_SCOPE_AGENT);
        }
    }
}

// ---- skip GEMM over all layers: relu(sum_i skip_w[i] @ xg[i]) -> in-place piece layout
__global__ __launch_bounds__(256) void skip_gemm_k(
    const unsigned short* __restrict__ xg_all,  // [40][65536][32] bf16
    const unsigned short* __restrict__ swb,     // [40][256][32] bf16
    unsigned short* __restrict__ sk)            // == xg_all base (in-place)
{
    __shared__ __align__(16) unsigned short lds[256 * 72];
    int tid = threadIdx.x;
    int w = tid >> 6, lane = tid & 63;
    int quad = lane >> 4, l15 = lane & 15;
    int p0 = blockIdx.x * 64;
    f32x4 zero = {0.f, 0.f, 0.f, 0.f};
    f32x4 acc[4][4];
#pragma unroll
    for (int a = 0; a < 4; ++a)
#pragma unroll
        for (int c = 0; c < 4; ++c) acc[a][c] = zero;

    const unsigned short* bbase = xg_all + ((size_t)(p0 + l15)) * 32 + quad * 8;
    const unsigned short* abase = swb + ((size_t)(w * 64 + l15)) * 32 + quad * 8;

    bf16x8 bcur[4], acur[4], bnxt[4], anxt[4];
#pragma unroll
    for (int ct = 0; ct < 4; ++ct) bcur[ct] = *(const bf16x8*)(bbase + ct * 512);
#pragma unroll
    for (int rt = 0; rt < 4; ++rt) acur[rt] = *(const bf16x8*)(abase + rt * 512);

#pragma unroll 2
    for (int i = 0; i < 40; ++i) {
        if (i < 39) {
            const unsigned short* bn = bbase + (size_t)(i + 1) * NPOS * 32;
            const unsigned short* an = abase + (size_t)(i + 1) * 8192;
#pragma unroll
            for (int ct = 0; ct < 4; ++ct) bnxt[ct] = *(const bf16x8*)(bn + ct * 512);
#pragma unroll
            for (int rt = 0; rt < 4; ++rt) anxt[rt] = *(const bf16x8*)(an + rt * 512);
        }
#pragma unroll
        for (int rt = 0; rt < 4; ++rt)
#pragma unroll
            for (int ct = 0; ct < 4; ++ct)
                acc[rt][ct] = __builtin_amdgcn_mfma_f32_16x16x32_bf16(acur[rt], bcur[ct], acc[rt][ct], 0, 0, 0);
#pragma unroll
        for (int ct = 0; ct < 4; ++ct) bcur[ct] = bnxt[ct];
#pragma unroll
        for (int rt = 0; rt < 4; ++rt) acur[rt] = anxt[rt];
    }

#pragma unroll
    for (int rt = 0; rt < 4; ++rt)
#pragma unroll
        for (int ct = 0; ct < 4; ++ct)
#pragma unroll
            for (int r = 0; r < 4; ++r) {
                float v = acc[rt][ct][r];
                v = v > 0.f ? v : 0.f;
                lds[(w * 64 + rt * 16 + quad * 4 + r) * 72 + ct * 16 + l15] = f32_bf16(v);
            }
    __syncthreads();
    {
        size_t pbbase = (size_t)(p0 >> 6) * 2048;
#pragma unroll
        for (int j = 0; j < 8; ++j) {
            int idx = tid + 256 * j;      // 2048 16B chunks
            int sc = idx >> 3, tc = idx & 7;
            int4 v = *(const int4*)(lds + sc * 72 + tc * 8);
            unsigned short* dst = sk + (size_t)(sc >> 5) * SK_PIECE + pbbase
                                     + (sc & 31) * 64 + tc * 8;
            *(int4*)dst = v;
        }
    }
}

// ---- FC split-K partials: block kb handles (sc = kb>>1, t-half = (kb&1)*512)
__global__ __launch_bounds__(256) void fc_part_k(
    const unsigned short* __restrict__ sk,    // in-place piece layout (see skip_gemm_k)
    const float* __restrict__ fw,             // [256][262144] fp32, k = sc*1024+t
    float* __restrict__ part)                 // [512][64][256]
{
    int tid = threadIdx.x;
    int w = tid >> 6, lane = tid & 63;
    int quad = lane >> 4, l15 = lane & 15;
    int kb = blockIdx.x;
    int sc = kb >> 1;
    int tbase = (kb & 1) * 512;
    f32x4 zero = {0.f, 0.f, 0.f, 0.f};
    f32x4 acc[4][4];
#pragma unroll
    for (int a = 0; a < 4; ++a)
#pragma unroll
        for (int c = 0; c < 4; ++c) acc[a][c] = zero;

    const unsigned short* skp = sk + (size_t)(sc >> 5) * SK_PIECE + (sc & 31) * 64;

    for (int it = 0; it < 16; ++it) {
        int t = tbase + it * 32 + quad * 8;
        bf16x8 af[4];
#pragma unroll
        for (int rt = 0; rt < 4; ++rt) {
            int bi = rt * 16 + l15;
            af[rt] = *(const bf16x8*)(skp + (size_t)(bi * 16 + (t >> 6)) * 2048 + (t & 63));
        }
#pragma unroll
        for (int ct = 0; ct < 4; ++ct) {
            bf16x8 bw = ldf8_bf16(fw + (size_t)(w * 64 + ct * 16 + l15) * 262144 + sc * 1024 + t);
#pragma unroll
            for (int rt = 0; rt < 4; ++rt)
                acc[rt][ct] = __builtin_amdgcn_mfma_f32_16x16x32_bf16(af[rt], bw, acc[rt][ct], 0, 0, 0);
        }
    }
#pragma unroll
    for (int rt = 0; rt < 4; ++rt)
#pragma unroll
        for (int ct = 0; ct < 4; ++ct)
#pragma unroll
            for (int r = 0; r < 4; ++r) {
                int bb = rt * 16 + quad * 4 + r;
                int cls = w * 64 + ct * 16 + l15;
                part[((size_t)kb * 64 + bb) * 256 + cls] = acc[rt][ct][r];
            }
}

__global__ void fc_reduce_k(const float* __restrict__ part,
                            const float* __restrict__ fb,
                            float* __restrict__ out) {
    int b = blockIdx.x, cls = threadIdx.x;
    float s = fb[cls];
    for (int kb = 0; kb < 512; ++kb)
        s += part[((size_t)kb * 64 + b) * 256 + cls];
    out[b * 256 + cls] = s;   // fp32 output
}

extern "C" void kernel_launch(void* const* d_in, const int* in_sizes, int n_in,
                              void* d_out, int out_size, void* d_ws, size_t ws_size,
                              hipStream_t stream) {
    const float* input    = (const float*)d_in[0];
    const float* start_w  = (const float*)d_in[1];
    const float* filter_w = (const float*)d_in[2];
    const float* gate_w   = (const float*)d_in[3];
    const float* res_w    = (const float*)d_in[4];
    const float* skip_w   = (const float*)d_in[5];
    const float* fc_w     = (const float*)d_in[6];
    const float* fc_b     = (const float*)d_in[7];
    float* out = (float*)d_out;

    // Overlay layout (phases A: fused layers, B: skip gemm, C: fc):
    //   [0, 160MB)        xg_all (A,B)   | sk = xg layers 0-7, in-place (B out, C in)
    //   [32MB, 64MB)      part (C)       | aliases xg layers 8-15, dead in C
    //   [160MB, 176MB)    xa 8MB + xb 8MB (A)
    //   [176MB, 176.5MB)  fgw (A)
    //   [176.5, 177.125)  swb (A write, B read)
    //   [178MB, +80KB)    rwb (A)
    //   [184MB, +4KB)     progress (A)
    const size_t REQUIRED = 192 * MB;
    if (ws_size < REQUIRED) {
        ws_probe_k<<<64, 256, 0, stream>>>(out, (float)(ws_size >> 20));
        return;
    }

    char* ws = (char*)d_ws;
    unsigned short* xg_all = (unsigned short*)(ws);             // 160MB
    unsigned short* sk     = (unsigned short*)(ws);             // 32MB in-place (B,C)
    float*          part   = (float*)(ws + 32 * MB);            // 32MB (phase C)
    float*          xa     = (float*)(ws + 160 * MB);           // 8MB (phase A)
    float*          xb     = (float*)(ws + 168 * MB);           // 8MB (phase A)
    unsigned short* fgw    = (unsigned short*)(ws + 176 * MB);  // 480KB (phase A)
    unsigned short* swb    = (unsigned short*)(ws + 176 * MB + 512 * 1024); // 640KB (A,B)
    unsigned short* rwb    = (unsigned short*)(ws + 178 * MB);  // 80KB (phase A)
    int*            progress = (int*)(ws + 184 * MB);           // 4KB (phase A)

    repack_fgw_k<<<960, 256, 0, stream>>>(filter_w, gate_w, fgw);
    repack_sw_k<<<1280, 256, 0, stream>>>(skip_w, swb);
    repack_rw_k<<<160, 256, 0, stream>>>(res_w, rwb);
    zero_progress_k<<<4, 256, 0, stream>>>(progress);
    start_conv_k<<<1024, 256, 0, stream>>>(input, start_w, xa);

    layers_fused_k<<<1024, 256, 0, stream>>>(xa, xb, fgw, rwb, xg_all, progress);

    skip_gemm_k<<<1024, 256, 0, stream>>>(xg_all, swb, sk);
    fc_part_k<<<512, 256, 0, stream>>>(sk, fc_w, part);
    fc_reduce_k<<<64, 256, 0, stream>>>(part, fc_b, out);
}

// Round 5
// 795.448 us; speedup vs baseline: 3.2064x; 3.2064x over previous
//
#include <hip/hip_runtime.h>
#include <stdint.h>

typedef short bf16x8 __attribute__((ext_vector_type(8)));
typedef short s4 __attribute__((ext_vector_type(4)));
typedef float f32x4 __attribute__((ext_vector_type(4)));

#define NPOS 65536  // B*L = 64*1024
#define MB (1024ull * 1024ull)
#define SK_PIECE 2097152  // shorts per 4MB piece of the in-place skip output

__device__ __forceinline__ unsigned short f32_bf16(float f) {
    union { float f; unsigned u; } v; v.f = f;
    unsigned u = v.u;
    u += 0x7fffu + ((u >> 16) & 1u);
    return (unsigned short)(u >> 16);
}

// 4 floats -> 4 bf16 via v_cvt_pk_bf16_f32 (RNE, matches f32_bf16)
__device__ __forceinline__ s4 pk4_bf16(float a, float b, float c, float d) {
    union { unsigned u[2]; s4 v; } r;
    asm("v_cvt_pk_bf16_f32 %0, %1, %2" : "=v"(r.u[0]) : "v"(a), "v"(b));
    asm("v_cvt_pk_bf16_f32 %0, %1, %2" : "=v"(r.u[1]) : "v"(c), "v"(d));
    return r.v;
}

// load 8 consecutive floats, round to bf16 fragment (scalar path)
__device__ __forceinline__ bf16x8 ldf8_bf16(const float* p) {
    const float4 lo = *(const float4*)p;
    const float4 hi = *(const float4*)(p + 4);
    bf16x8 v;
    v[0] = (short)f32_bf16(lo.x); v[1] = (short)f32_bf16(lo.y);
    v[2] = (short)f32_bf16(lo.z); v[3] = (short)f32_bf16(lo.w);
    v[4] = (short)f32_bf16(hi.x); v[5] = (short)f32_bf16(hi.y);
    v[6] = (short)f32_bf16(hi.z); v[7] = (short)f32_bf16(hi.w);
    return v;
}

// fallback: encode ws_size (MiB) into output so a failing run tells us the budget
__global__ void ws_probe_k(float* __restrict__ out, float mib) {
    int i = blockIdx.x * 256 + threadIdx.x;
    if (i < 16384) out[i] = mib;
}

// ---- repack filter+gate weights (fp32 in) -> bf16 [layer][tap][oc 0..63 (f|g)][ic 0..31]
__global__ void repack_fgw_k(const float* __restrict__ fw,
                             const float* __restrict__ gw,
                             unsigned short* __restrict__ out) {
    int idx = blockIdx.x * 256 + threadIdx.x;  // < 40*3*64*32 = 245760
    int ic = idx & 31;
    int r1 = idx >> 5;
    int oc = r1 & 63;
    int r2 = r1 >> 6;      // i*3 + k
    int k  = r2 % 3;
    int i  = r2 / 3;
    const float* src = (oc < 32) ? fw : gw;
    out[idx] = f32_bf16(src[(((i * 32 + (oc & 31)) * 32 + ic) * 3) + k]);
}

// ---- repack skip weights fp32 -> bf16, same layout [40][256][32]
__global__ void repack_sw_k(const float* __restrict__ sw,
                            unsigned short* __restrict__ out) {
    int idx = blockIdx.x * 256 + threadIdx.x;  // < 40*256*32 = 327680
    out[idx] = f32_bf16(sw[idx]);
}

// ---- repack residual weights fp32 -> bf16 linear [40][32][32]
__global__ void repack_rw_k(const float* __restrict__ rw,
                            unsigned short* __restrict__ out) {
    int idx = blockIdx.x * 256 + threadIdx.x;  // < 40*32*32 = 40960
    out[idx] = f32_bf16(rw[idx]);
}

// ============================================================================
// Row-resident fused WaveNet: ONE block per batch row (64 blocks x 512 thr).
// All 40 layers stay in the block: x (bf16) lives in LDS, the fp32 residual
// accumulator lives in registers, only xg leaves to global. No cross-block
// dependencies exist (taps reach +-d <= 512 < row length 1024, zero-padded
// at row edges), so all sync is __syncthreads (2 per layer).
//
// Register ownership per lane (quad = lane>>4, l15 = lane&15), per group g:
//   pos = (w*8+g)*16 + l15
//   ch j<4 : quad*4+j      ch j>=4: 16+quad*4+(j-4)
// which exactly matches the 16x16x32 MFMA C-fragment rows, so the residual
// update is register-local adds.
//
// xb16 LDS layout: [pos][32ch] bf16, 4x16B chunks per pos, chunk XOR-swizzled
// by (pos&3) -> tap ds_read_b128 ~conflict-free.
// ============================================================================
__global__ __launch_bounds__(512, 2) void wavenet_rows_k(
    const float* __restrict__ in,               // [64][2][1024]
    const float* __restrict__ stw,              // [32][2] start conv weights
    const unsigned short* __restrict__ fgw_all, // [40][3][64][32] bf16
    const unsigned short* __restrict__ rwb_all, // [40][32][32] bf16
    unsigned short* __restrict__ xg_all)        // [40][65536][32] bf16
{
    __shared__ __align__(16) unsigned short xb16[1024 * 32];   // 64 KB
    __shared__ __align__(16) unsigned short stage[8 * 640];    // 10 KB (per-wave [16][40])

    const int tid = threadIdx.x;
    const int w = tid >> 6, lane = tid & 63;
    const int quad = lane >> 4, l15 = lane & 15;
    const int b = blockIdx.x;
    const f32x4 zero = {0.f, 0.f, 0.f, 0.f};
    const int c0lo = quad >> 1;              // chunk of ch quad*4
    const int bi   = (quad & 1) * 4;         // short offset within chunk

    float xreg[8][8];

    // ---- start conv: x0 = stw @ input (2 -> 32 ch), into registers + LDS
    {
        float s0[8], s1[8];
#pragma unroll
        for (int j = 0; j < 8; ++j) {
            int c = (j < 4) ? (quad * 4 + j) : (16 + quad * 4 + (j - 4));
            s0[j] = stw[c * 2 + 0];
            s1[j] = stw[c * 2 + 1];
        }
#pragma unroll
        for (int g = 0; g < 8; ++g) {
            int t = (w * 8 + g) * 16 + l15;
            float i0 = in[(b * 2 + 0) * 1024 + t];
            float i1 = in[(b * 2 + 1) * 1024 + t];
#pragma unroll
            for (int j = 0; j < 8; ++j) xreg[g][j] = s0[j] * i0 + s1[j] * i1;
            // write to swizzled LDS
            s4 lo = pk4_bf16(xreg[g][0], xreg[g][1], xreg[g][2], xreg[g][3]);
            s4 hi = pk4_bf16(xreg[g][4], xreg[g][5], xreg[g][6], xreg[g][7]);
            int base = t * 32;
            *(s4*)(xb16 + base + ((c0lo ^ (t & 3)) * 8) + bi) = lo;
            *(s4*)(xb16 + base + (((c0lo + 2) ^ (t & 3)) * 8) + bi) = hi;
        }
    }
    __syncthreads();

    unsigned short* const st = stage + w * 640;   // this wave's [16][40] tile

#pragma unroll 1
    for (int i = 0; i < 40; ++i) {
        const int d = 1 << (i % 10);
        const unsigned short* fgw = fgw_all + (size_t)i * 6144;
        unsigned short* xg = xg_all + (size_t)i * ((size_t)NPOS * 32)
                                    + (size_t)b * 1024 * 32;
        const bool dores = (i < 39);

        // ---- preload this layer's weight fragments (L2-hot, lane-indexed)
        bf16x8 wf[3][2], wg[3][2], wr[2];
#pragma unroll
        for (int k = 0; k < 3; ++k) {
            const unsigned short* wb = fgw + k * 2048;
#pragma unroll
            for (int mt = 0; mt < 2; ++mt) {
                wf[k][mt] = *(const bf16x8*)(wb + (mt * 16 + l15) * 32 + quad * 8);
                wg[k][mt] = *(const bf16x8*)(wb + ((mt + 2) * 16 + l15) * 32 + quad * 8);
            }
        }
        if (dores) {
            const unsigned short* rwb = rwb_all + (size_t)i * 1024;
#pragma unroll
            for (int rt = 0; rt < 2; ++rt)
                wr[rt] = *(const bf16x8*)(rwb + (rt * 16 + l15) * 32 + quad * 8);
        }

        // ---- phase 1: per group: taps -> conv MFMA -> gate -> stage ->
        //      res MFMA (reg-local x update) + coalesced xg store.
        //      Reads ONLY old xb16; writes only stage (per-wave) + global.
#pragma unroll
        for (int g = 0; g < 8; ++g) {
            const int tg = (w * 8 + g) * 16;
            const int tc = tg + l15;

            bf16x8 bfr[3];
            bf16x8 zz; 
#pragma unroll
            for (int j = 0; j < 8; ++j) zz[j] = 0;
            bfr[1] = *(const bf16x8*)(xb16 + tc * 32 + ((quad ^ (tc & 3)) * 8));
            {
                int ts = tc - d, tsc = ts & 1023;
                bf16x8 rv = *(const bf16x8*)(xb16 + tsc * 32 + ((quad ^ (tsc & 3)) * 8));
                bfr[0] = (ts >= 0) ? rv : zz;
            }
            {
                int ts = tc + d, tsc = ts & 1023;
                bf16x8 rv = *(const bf16x8*)(xb16 + tsc * 32 + ((quad ^ (tsc & 3)) * 8));
                bfr[2] = (ts < 1024) ? rv : zz;
            }

            f32x4 accf[2] = {zero, zero};
            f32x4 accg[2] = {zero, zero};
#pragma unroll
            for (int k = 0; k < 3; ++k) {
#pragma unroll
                for (int mt = 0; mt < 2; ++mt) {
                    accf[mt] = __builtin_amdgcn_mfma_f32_16x16x32_bf16(wf[k][mt], bfr[k], accf[mt], 0, 0, 0);
                    accg[mt] = __builtin_amdgcn_mfma_f32_16x16x32_bf16(wg[k][mt], bfr[k], accg[mt], 0, 0, 0);
                }
            }

            // gated activation -> stage [pos l15][ch mt*16+quad*4+r] (pad 40)
#pragma unroll
            for (int mt = 0; mt < 2; ++mt) {
                float gv0, gv1, gv2, gv3;
                {
                    float o[4];
#pragma unroll
                    for (int r = 0; r < 4; ++r) {
                        float fv = accf[mt][r], gg = accg[mt][r];
                        float ef = __expf(2.0f * fv);
                        float th = 1.0f - 2.0f * __builtin_amdgcn_rcpf(1.0f + ef);
                        float eg = __expf(-gg);
                        float sg = __builtin_amdgcn_rcpf(1.0f + eg);
                        o[r] = th * sg;
                    }
                    gv0 = o[0]; gv1 = o[1]; gv2 = o[2]; gv3 = o[3];
                }
                *(s4*)(st + l15 * 40 + mt * 16 + quad * 4) = pk4_bf16(gv0, gv1, gv2, gv3);
            }

            // res 1x1 GEMM: B-frag from stage (k=ch quad*8..+7, n=pos l15)
            if (dores) {
                bf16x8 bx = *(const bf16x8*)(st + l15 * 40 + quad * 8);
                f32x4 accr[2] = {zero, zero};
#pragma unroll
                for (int rt = 0; rt < 2; ++rt)
                    accr[rt] = __builtin_amdgcn_mfma_f32_16x16x32_bf16(wr[rt], bx, accr[rt], 0, 0, 0);
#pragma unroll
                for (int rt = 0; rt < 2; ++rt)
#pragma unroll
                    for (int r = 0; r < 4; ++r)
                        xreg[g][rt * 4 + r] += accr[rt][r];
            }

            // coalesced xg store: 64 lanes cover [16 pos][32 ch] = 1 KB
            {
                int pp = lane >> 2, cc = (lane & 3) * 8;
                int4 v = *(const int4*)(st + pp * 40 + cc);
                *(int4*)(xg + (size_t)(tg + pp) * 32 + cc) = v;
            }
        }
        __syncthreads();   // all waves done reading old xb16

        // ---- phase 2: publish new x (bf16) to LDS
        if (dores) {
#pragma unroll
            for (int g = 0; g < 8; ++g) {
                int t = (w * 8 + g) * 16 + l15;
                s4 lo = pk4_bf16(xreg[g][0], xreg[g][1], xreg[g][2], xreg[g][3]);
                s4 hi = pk4_bf16(xreg[g][4], xreg[g][5], xreg[g][6], xreg[g][7]);
                int base = t * 32;
                *(s4*)(xb16 + base + ((c0lo ^ (t & 3)) * 8) + bi) = lo;
                *(s4*)(xb16 + base + (((c0lo + 2) ^ (t & 3)) * 8) + bi) = hi;
            }
            __syncthreads();
        }
    }
}

// ---- skip GEMM over all layers: relu(sum_i skip_w[i] @ xg[i]) -> in-place piece layout
__global__ __launch_bounds__(256) void skip_gemm_k(
    const unsigned short* __restrict__ xg_all,  // [40][65536][32] bf16
    const unsigned short* __restrict__ swb,     // [40][256][32] bf16
    unsigned short* __restrict__ sk)            // == xg_all base (in-place)
{
    __shared__ __align__(16) unsigned short lds[256 * 72];
    int tid = threadIdx.x;
    int w = tid >> 6, lane = tid & 63;
    int quad = lane >> 4, l15 = lane & 15;
    int p0 = blockIdx.x * 64;
    f32x4 zero = {0.f, 0.f, 0.f, 0.f};
    f32x4 acc[4][4];
#pragma unroll
    for (int a = 0; a < 4; ++a)
#pragma unroll
        for (int c = 0; c < 4; ++c) acc[a][c] = zero;

    const unsigned short* bbase = xg_all + ((size_t)(p0 + l15)) * 32 + quad * 8;
    const unsigned short* abase = swb + ((size_t)(w * 64 + l15)) * 32 + quad * 8;

    bf16x8 bcur[4], acur[4], bnxt[4], anxt[4];
#pragma unroll
    for (int ct = 0; ct < 4; ++ct) bcur[ct] = *(const bf16x8*)(bbase + ct * 512);
#pragma unroll
    for (int rt = 0; rt < 4; ++rt) acur[rt] = *(const bf16x8*)(abase + rt * 512);

#pragma unroll 2
    for (int i = 0; i < 40; ++i) {
        if (i < 39) {
            const unsigned short* bn = bbase + (size_t)(i + 1) * NPOS * 32;
            const unsigned short* an = abase + (size_t)(i + 1) * 8192;
#pragma unroll
            for (int ct = 0; ct < 4; ++ct) bnxt[ct] = *(const bf16x8*)(bn + ct * 512);
#pragma unroll
            for (int rt = 0; rt < 4; ++rt) anxt[rt] = *(const bf16x8*)(an + rt * 512);
        }
#pragma unroll
        for (int rt = 0; rt < 4; ++rt)
#pragma unroll
            for (int ct = 0; ct < 4; ++ct)
                acc[rt][ct] = __builtin_amdgcn_mfma_f32_16x16x32_bf16(acur[rt], bcur[ct], acc[rt][ct], 0, 0, 0);
#pragma unroll
        for (int ct = 0; ct < 4; ++ct) bcur[ct] = bnxt[ct];
#pragma unroll
        for (int rt = 0; rt < 4; ++rt) acur[rt] = anxt[rt];
    }

#pragma unroll
    for (int rt = 0; rt < 4; ++rt)
#pragma unroll
        for (int ct = 0; ct < 4; ++ct)
#pragma unroll
            for (int r = 0; r < 4; ++r) {
                float v = acc[rt][ct][r];
                v = v > 0.f ? v : 0.f;
                lds[(w * 64 + rt * 16 + quad * 4 + r) * 72 + ct * 16 + l15] = f32_bf16(v);
            }
    __syncthreads();
    {
        size_t pbbase = (size_t)(p0 >> 6) * 2048;
#pragma unroll
        for (int j = 0; j < 8; ++j) {
            int idx = tid + 256 * j;      // 2048 16B chunks
            int sc = idx >> 3, tc = idx & 7;
            int4 v = *(const int4*)(lds + sc * 72 + tc * 8);
            unsigned short* dst = sk + (size_t)(sc >> 5) * SK_PIECE + pbbase
                                     + (sc & 31) * 64 + tc * 8;
            *(int4*)dst = v;
        }
    }
}

// ---- FC split-K partials: block kb handles (sc = kb>>1, t-half = (kb&1)*512)
__global__ __launch_bounds__(256) void fc_part_k(
    const unsigned short* __restrict__ sk,    // in-place piece layout (see skip_gemm_k)
    const float* __restrict__ fw,             // [256][262144] fp32, k = sc*1024+t
    float* __restrict__ part)                 // [512][64][256]
{
    int tid = threadIdx.x;
    int w = tid >> 6, lane = tid & 63;
    int quad = lane >> 4, l15 = lane & 15;
    int kb = blockIdx.x;
    int sc = kb >> 1;
    int tbase = (kb & 1) * 512;
    f32x4 zero = {0.f, 0.f, 0.f, 0.f};
    f32x4 acc[4][4];
#pragma unroll
    for (int a = 0; a < 4; ++a)
#pragma unroll
        for (int c = 0; c < 4; ++c) acc[a][c] = zero;

    const unsigned short* skp = sk + (size_t)(sc >> 5) * SK_PIECE + (sc & 31) * 64;

    for (int it = 0; it < 16; ++it) {
        int t = tbase + it * 32 + quad * 8;
        bf16x8 af[4];
#pragma unroll
        for (int rt = 0; rt < 4; ++rt) {
            int bi = rt * 16 + l15;
            af[rt] = *(const bf16x8*)(skp + (size_t)(bi * 16 + (t >> 6)) * 2048 + (t & 63));
        }
#pragma unroll
        for (int ct = 0; ct < 4; ++ct) {
            bf16x8 bw = ldf8_bf16(fw + (size_t)(w * 64 + ct * 16 + l15) * 262144 + sc * 1024 + t);
#pragma unroll
            for (int rt = 0; rt < 4; ++rt)
                acc[rt][ct] = __builtin_amdgcn_mfma_f32_16x16x32_bf16(af[rt], bw, acc[rt][ct], 0, 0, 0);
        }
    }
#pragma unroll
    for (int rt = 0; rt < 4; ++rt)
#pragma unroll
        for (int ct = 0; ct < 4; ++ct)
#pragma unroll
            for (int r = 0; r < 4; ++r) {
                int bb = rt * 16 + quad * 4 + r;
                int cls = w * 64 + ct * 16 + l15;
                part[((size_t)kb * 64 + bb) * 256 + cls] = acc[rt][ct][r];
            }
}

__global__ void fc_reduce_k(const float* __restrict__ part,
                            const float* __restrict__ fb,
                            float* __restrict__ out) {
    int b = blockIdx.x, cls = threadIdx.x;
    float s = fb[cls];
    for (int kb = 0; kb < 512; ++kb)
        s += part[((size_t)kb * 64 + b) * 256 + cls];
    out[b * 256 + cls] = s;   // fp32 output
}

extern "C" void kernel_launch(void* const* d_in, const int* in_sizes, int n_in,
                              void* d_out, int out_size, void* d_ws, size_t ws_size,
                              hipStream_t stream) {
    const float* input    = (const float*)d_in[0];
    const float* start_w  = (const float*)d_in[1];
    const float* filter_w = (const float*)d_in[2];
    const float* gate_w   = (const float*)d_in[3];
    const float* res_w    = (const float*)d_in[4];
    const float* skip_w   = (const float*)d_in[5];
    const float* fc_w     = (const float*)d_in[6];
    const float* fc_b     = (const float*)d_in[7];
    float* out = (float*)d_out;

    // Overlay layout (phases A: fused rows, B: skip gemm, C: fc):
    //   [0, 160MB)        xg_all (A,B)   | sk = xg layers 0-7, in-place (B out, C in)
    //   [32MB, 64MB)      part (C)       | aliases xg layers 8-15, dead in C
    //   [176MB, 176.5MB)  fgw (A)
    //   [176.5, 177.125)  swb (A write, B read)
    //   [178MB, +80KB)    rwb (A)
    const size_t REQUIRED = 192 * MB;
    if (ws_size < REQUIRED) {
        ws_probe_k<<<64, 256, 0, stream>>>(out, (float)(ws_size >> 20));
        return;
    }

    char* ws = (char*)d_ws;
    unsigned short* xg_all = (unsigned short*)(ws);             // 160MB
    unsigned short* sk     = (unsigned short*)(ws);             // 32MB in-place (B,C)
    float*          part   = (float*)(ws + 32 * MB);            // 32MB (phase C)
    unsigned short* fgw    = (unsigned short*)(ws + 176 * MB);  // 480KB (phase A)
    unsigned short* swb    = (unsigned short*)(ws + 176 * MB + 512 * 1024); // 640KB (A,B)
    unsigned short* rwb    = (unsigned short*)(ws + 178 * MB);  // 80KB (phase A)

    repack_fgw_k<<<960, 256, 0, stream>>>(filter_w, gate_w, fgw);
    repack_sw_k<<<1280, 256, 0, stream>>>(skip_w, swb);
    repack_rw_k<<<160, 256, 0, stream>>>(res_w, rwb);

    wavenet_rows_k<<<64, 512, 0, stream>>>(input, start_w, fgw, rwb, xg_all);

    skip_gemm_k<<<1024, 256, 0, stream>>>(xg_all, swb, sk);
    fc_part_k<<<512, 256, 0, stream>>>(sk, fc_w, part);
    fc_reduce_k<<<64, 256, 0, stream>>>(part, fc_b, out);
}